// Round 1
// baseline (1282.440 us; speedup 1.0000x reference)
//
#include <hip/hip_runtime.h>
#include <hip/hip_bf16.h>

// GraphLayer: B=8, N=2048, D=512, all fp32.
//   Q = x@Wq^T + bq; K = x@Wk^T + bk; V = x@Wv^T + bv
//   W = adj * exp(Q K^T);  out = (W @ V) / rowsum(W)
//
// Round 1: fp32 correctness-first, tiled SGEMMs (no fp32 MFMA on CDNA4).
//   proj   : NT GEMM (dot-of-rows), M=B*N=16384, K=512, O=512  (x3)
//   scores : NT GEMM per batch, 2048x2048x512, epilogue adj*exp -> W in ws
//   agg    : NN GEMM per batch, 2048x512x2048, den accumulated in k-loop,
//            epilogue divide. No atomics, deterministic.
// Workspace: Q|K|V (3 * 33.55MB) + W (134.2MB) = 224 MiB.

#define TILE 128
#define BK 16
#define LDSP (TILE + 4)   // pad: rows start 16B-aligned (132*4=528=33*16)

#define BATCH 8
#define SEQ   2048
#define DIM   512

// ---------------------------------------------------------------- proj ----
// out[m][o] = sum_d X[m][d] * W[o][d] + bias[o]
__global__ __launch_bounds__(256) void proj_kernel(
    const float* __restrict__ X, const float* __restrict__ Wt,
    const float* __restrict__ bias, float* __restrict__ out)
{
  __shared__ float As[BK][LDSP];
  __shared__ float Bs[BK][LDSP];
  const int tid = threadIdx.x;
  const int tx = tid & 15;
  const int ty = tid >> 4;
  const int m0 = blockIdx.y * TILE;
  const int n0 = blockIdx.x * TILE;

  float c[8][8];
#pragma unroll
  for (int i = 0; i < 8; ++i)
#pragma unroll
    for (int j = 0; j < 8; ++j) c[i][j] = 0.f;

  for (int k0 = 0; k0 < DIM; k0 += BK) {
#pragma unroll
    for (int l = 0; l < 2; ++l) {
      int f = tid + l * 256;
      int row = f >> 2;
      int c4 = (f & 3) << 2;
      float4 va = *(const float4*)(X + (size_t)(m0 + row) * DIM + k0 + c4);
      As[c4 + 0][row] = va.x; As[c4 + 1][row] = va.y;
      As[c4 + 2][row] = va.z; As[c4 + 3][row] = va.w;
      float4 vb = *(const float4*)(Wt + (size_t)(n0 + row) * DIM + k0 + c4);
      Bs[c4 + 0][row] = vb.x; Bs[c4 + 1][row] = vb.y;
      Bs[c4 + 2][row] = vb.z; Bs[c4 + 3][row] = vb.w;
    }
    __syncthreads();
#pragma unroll
    for (int k = 0; k < BK; ++k) {
      float4 a0 = *(const float4*)(&As[k][ty * 4]);
      float4 a1 = *(const float4*)(&As[k][64 + ty * 4]);
      float4 b0 = *(const float4*)(&Bs[k][tx * 4]);
      float4 b1 = *(const float4*)(&Bs[k][64 + tx * 4]);
      float a[8] = {a0.x, a0.y, a0.z, a0.w, a1.x, a1.y, a1.z, a1.w};
      float b[8] = {b0.x, b0.y, b0.z, b0.w, b1.x, b1.y, b1.z, b1.w};
#pragma unroll
      for (int i = 0; i < 8; ++i)
#pragma unroll
        for (int j = 0; j < 8; ++j) c[i][j] = fmaf(a[i], b[j], c[i][j]);
    }
    __syncthreads();
  }

#pragma unroll
  for (int i = 0; i < 8; ++i) {
    int m = m0 + ((i < 4) ? (ty * 4 + i) : (64 + ty * 4 + (i - 4)));
#pragma unroll
    for (int jh = 0; jh < 2; ++jh) {
      int n = n0 + ((jh == 0) ? (tx * 4) : (64 + tx * 4));
      float4 bb = *(const float4*)(bias + n);
      float4 v;
      v.x = c[i][jh * 4 + 0] + bb.x;
      v.y = c[i][jh * 4 + 1] + bb.y;
      v.z = c[i][jh * 4 + 2] + bb.z;
      v.w = c[i][jh * 4 + 3] + bb.w;
      *(float4*)(out + (size_t)m * DIM + n) = v;
    }
  }
}

// -------------------------------------------------------------- scores ----
// Wout[b][q][k] = adj[b][q][k] * exp( sum_d Q[b][q][d] * K[b][k][d] )
__global__ __launch_bounds__(256) void scores_kernel(
    const float* __restrict__ Q, const float* __restrict__ Km,
    const float* __restrict__ adj, float* __restrict__ Wout)
{
  __shared__ float As[BK][LDSP];
  __shared__ float Bs[BK][LDSP];
  const int tid = threadIdx.x;
  const int tx = tid & 15;
  const int ty = tid >> 4;
  const int b = blockIdx.z;
  const int m0 = blockIdx.y * TILE;   // q tile
  const int n0 = blockIdx.x * TILE;   // key tile
  const float* Qb = Q + (size_t)b * SEQ * DIM;
  const float* Kb = Km + (size_t)b * SEQ * DIM;

  float c[8][8];
#pragma unroll
  for (int i = 0; i < 8; ++i)
#pragma unroll
    for (int j = 0; j < 8; ++j) c[i][j] = 0.f;

  for (int k0 = 0; k0 < DIM; k0 += BK) {
#pragma unroll
    for (int l = 0; l < 2; ++l) {
      int f = tid + l * 256;
      int row = f >> 2;
      int c4 = (f & 3) << 2;
      float4 va = *(const float4*)(Qb + (size_t)(m0 + row) * DIM + k0 + c4);
      As[c4 + 0][row] = va.x; As[c4 + 1][row] = va.y;
      As[c4 + 2][row] = va.z; As[c4 + 3][row] = va.w;
      float4 vb = *(const float4*)(Kb + (size_t)(n0 + row) * DIM + k0 + c4);
      Bs[c4 + 0][row] = vb.x; Bs[c4 + 1][row] = vb.y;
      Bs[c4 + 2][row] = vb.z; Bs[c4 + 3][row] = vb.w;
    }
    __syncthreads();
#pragma unroll
    for (int k = 0; k < BK; ++k) {
      float4 a0 = *(const float4*)(&As[k][ty * 4]);
      float4 a1 = *(const float4*)(&As[k][64 + ty * 4]);
      float4 b0 = *(const float4*)(&Bs[k][tx * 4]);
      float4 b1 = *(const float4*)(&Bs[k][64 + tx * 4]);
      float a[8] = {a0.x, a0.y, a0.z, a0.w, a1.x, a1.y, a1.z, a1.w};
      float bb[8] = {b0.x, b0.y, b0.z, b0.w, b1.x, b1.y, b1.z, b1.w};
#pragma unroll
      for (int i = 0; i < 8; ++i)
#pragma unroll
        for (int j = 0; j < 8; ++j) c[i][j] = fmaf(a[i], bb[j], c[i][j]);
    }
    __syncthreads();
  }

  const float* adjb = adj + (size_t)b * SEQ * SEQ;
  float* wb = Wout + (size_t)b * SEQ * SEQ;
#pragma unroll
  for (int i = 0; i < 8; ++i) {
    int m = m0 + ((i < 4) ? (ty * 4 + i) : (64 + ty * 4 + (i - 4)));
#pragma unroll
    for (int jh = 0; jh < 2; ++jh) {
      int n = n0 + ((jh == 0) ? (tx * 4) : (64 + tx * 4));
      float4 av = *(const float4*)(adjb + (size_t)m * SEQ + n);
      float4 v;
      v.x = av.x * __expf(c[i][jh * 4 + 0]);
      v.y = av.y * __expf(c[i][jh * 4 + 1]);
      v.z = av.z * __expf(c[i][jh * 4 + 2]);
      v.w = av.w * __expf(c[i][jh * 4 + 3]);
      *(float4*)(wb + (size_t)m * SEQ + n) = v;
    }
  }
}

// ----------------------------------------------------------------- agg ----
// out[b][q][d] = (sum_k W[b][q][k] * V[b][k][d]) / (sum_k W[b][q][k])
__global__ __launch_bounds__(256) void agg_kernel(
    const float* __restrict__ Wm, const float* __restrict__ V,
    float* __restrict__ out)
{
  __shared__ float As[BK][LDSP];
  __shared__ float Bs[BK][LDSP];
  const int tid = threadIdx.x;
  const int tx = tid & 15;
  const int ty = tid >> 4;
  const int b = blockIdx.z;
  const int m0 = blockIdx.y * TILE;   // q tile
  const int n0 = blockIdx.x * TILE;   // d tile (0..511)
  const float* Wb = Wm + (size_t)b * SEQ * SEQ;
  const float* Vb = V + (size_t)b * SEQ * DIM;

  float c[8][8];
  float den[8];
#pragma unroll
  for (int i = 0; i < 8; ++i) {
    den[i] = 0.f;
#pragma unroll
    for (int j = 0; j < 8; ++j) c[i][j] = 0.f;
  }

  for (int k0 = 0; k0 < SEQ; k0 += BK) {
#pragma unroll
    for (int l = 0; l < 2; ++l) {
      int f = tid + l * 256;
      // A tile: 128 rows x 16 cols of W (transpose to As[k][m])
      int row = f >> 2;
      int c4 = (f & 3) << 2;
      float4 va = *(const float4*)(Wb + (size_t)(m0 + row) * SEQ + k0 + c4);
      As[c4 + 0][row] = va.x; As[c4 + 1][row] = va.y;
      As[c4 + 2][row] = va.z; As[c4 + 3][row] = va.w;
      // B tile: 16 rows x 128 cols of V (natural layout)
      int brow = f >> 5;
      int bcol = (f & 31) << 2;
      float4 vb = *(const float4*)(Vb + (size_t)(k0 + brow) * DIM + n0 + bcol);
      *(float4*)(&Bs[brow][bcol]) = vb;
    }
    __syncthreads();
#pragma unroll
    for (int k = 0; k < BK; ++k) {
      float4 a0 = *(const float4*)(&As[k][ty * 4]);
      float4 a1 = *(const float4*)(&As[k][64 + ty * 4]);
      float4 b0 = *(const float4*)(&Bs[k][tx * 4]);
      float4 b1 = *(const float4*)(&Bs[k][64 + tx * 4]);
      float a[8] = {a0.x, a0.y, a0.z, a0.w, a1.x, a1.y, a1.z, a1.w};
      float bb[8] = {b0.x, b0.y, b0.z, b0.w, b1.x, b1.y, b1.z, b1.w};
#pragma unroll
      for (int i = 0; i < 8; ++i) {
        den[i] += a[i];
#pragma unroll
        for (int j = 0; j < 8; ++j) c[i][j] = fmaf(a[i], bb[j], c[i][j]);
      }
    }
    __syncthreads();
  }

  float* outb = out + (size_t)b * SEQ * DIM;
#pragma unroll
  for (int i = 0; i < 8; ++i) {
    int m = m0 + ((i < 4) ? (ty * 4 + i) : (64 + ty * 4 + (i - 4)));
    float rd = 1.0f / den[i];
#pragma unroll
    for (int jh = 0; jh < 2; ++jh) {
      int n = n0 + ((jh == 0) ? (tx * 4) : (64 + tx * 4));
      float4 v;
      v.x = c[i][jh * 4 + 0] * rd;
      v.y = c[i][jh * 4 + 1] * rd;
      v.z = c[i][jh * 4 + 2] * rd;
      v.w = c[i][jh * 4 + 3] * rd;
      *(float4*)(outb + (size_t)m * DIM + n) = v;
    }
  }
}

// -------------------------------------------------------------- launch ----
extern "C" void kernel_launch(void* const* d_in, const int* in_sizes, int n_in,
                              void* d_out, int out_size, void* d_ws, size_t ws_size,
                              hipStream_t stream) {
  const float* x   = (const float*)d_in[0];
  const float* adj = (const float*)d_in[1];
  const float* Wq  = (const float*)d_in[2];
  const float* bq  = (const float*)d_in[3];
  const float* Wk  = (const float*)d_in[4];
  const float* bk  = (const float*)d_in[5];
  const float* Wv  = (const float*)d_in[6];
  const float* bv  = (const float*)d_in[7];
  float* out = (float*)d_out;

  const size_t qkv_elems = (size_t)BATCH * SEQ * DIM;      // 8,388,608
  float* Q  = (float*)d_ws;
  float* Km = Q + qkv_elems;
  float* V  = Km + qkv_elems;
  float* Wt = V + qkv_elems;                                // B*N*N floats

  // Projections: M = B*N = 16384 rows, grid (O/128, M/128)
  dim3 pgrid(DIM / TILE, (BATCH * SEQ) / TILE);
  proj_kernel<<<pgrid, 256, 0, stream>>>(x, Wq, bq, Q);
  proj_kernel<<<pgrid, 256, 0, stream>>>(x, Wk, bk, Km);
  proj_kernel<<<pgrid, 256, 0, stream>>>(x, Wv, bv, V);

  // Scores: per batch 2048x2048, K=512
  dim3 sgrid(SEQ / TILE, SEQ / TILE, BATCH);
  scores_kernel<<<sgrid, 256, 0, stream>>>(Q, Km, adj, Wt);

  // Aggregate: per batch 2048x512, K=2048
  dim3 agrid(DIM / TILE, SEQ / TILE, BATCH);
  agg_kernel<<<agrid, 256, 0, stream>>>(Wt, V, out);
}

// Round 2
// 505.230 us; speedup vs baseline: 2.5383x; 2.5383x over previous
//
#include <hip/hip_runtime.h>
#include <hip/hip_bf16.h>

// GraphLayer B=8,N=2048,D=512 — Round 2: all GEMMs on bf16 MFMA (16x16x32).
//   Q,K: split-bf16 (hi+lo) end-to-end -> near-fp32 logits (exp is sensitive).
//   W = adj*exp(QK^T) stored bf16; den = rowsum of the SAME bf16 values
//   (common-mode rounding cancels in the normalization).
//   V stored bf16 pre-transposed (Vt[d][seq]) so agg is a pure NT GEMM.
// All GEMMs: m97 structure — 128x128 tile, BK=32, 256 thr (2x2 waves of 64,
// each wave 4x4 subtiles of 16x16), global_load_lds width=16 staging,
// single-buffer 2-barrier K-loop.

#define BATCH 8
#define SEQ   2048
#define DIM   512
#define MSEQ  (BATCH * SEQ)   // 16384

typedef __attribute__((ext_vector_type(8))) short bf16x8;
typedef __attribute__((ext_vector_type(4))) float f32x4;

__device__ __forceinline__ unsigned short f2bf(float f) {
  __hip_bfloat16 h = __float2bfloat16(f);
  union { __hip_bfloat16 h; unsigned short u; } c; c.h = h; return c.u;
}
__device__ __forceinline__ float bf2f(unsigned short u) {
  union { unsigned int u; float f; } c; c.u = ((unsigned int)u) << 16; return c.f;
}

__device__ __forceinline__ void async16(const unsigned short* g, unsigned short* l) {
  __builtin_amdgcn_global_load_lds(
      (const __attribute__((address_space(1))) void*)g,
      (__attribute__((address_space(3))) void*)l, 16, 0, 0);
}

// ---------------------------------------------------------------- core ----
// acc[i][j] += (Ahi+Alo)[m][k] * (Bhi+Blo)[n][k]  (NT, both row-major over k)
// A/B pointers pre-offset to the block's first row. LDS tiles 128x32 bf16.
template <bool SPLIT>
__device__ __forceinline__ void gemm_mainloop(
    const unsigned short* __restrict__ Ahi, const unsigned short* __restrict__ Alo,
    const unsigned short* __restrict__ Bhi, const unsigned short* __restrict__ Blo,
    int lda, int ldb, int K,
    unsigned short* sAhi, unsigned short* sAlo,
    unsigned short* sBhi, unsigned short* sBlo,
    f32x4 acc[4][4])
{
  const int tid  = threadIdx.x;
  const int lane = tid & 63;
  const int w    = tid >> 6;
  const int wm   = w >> 1, wn = w & 1;
  const int quad = lane >> 4, fcol = lane & 15;
  const int srow = lane >> 2;          // 0..15 within a 16-row chunk
  const int scol = (lane & 3) * 8;     // ushort offset, 16B granules

  for (int k0 = 0; k0 < K; k0 += 32) {
#pragma unroll
    for (int inst = 0; inst < 2; ++inst) {
      const int rbase  = w * 32 + inst * 16;
      const int r      = rbase + srow;
      const int ldsoff = rbase * 32;   // row stride 32 ushorts
      async16(Ahi + (size_t)r * lda + k0 + scol, sAhi + ldsoff);
      async16(Bhi + (size_t)r * ldb + k0 + scol, sBhi + ldsoff);
      if constexpr (SPLIT) {
        async16(Alo + (size_t)r * lda + k0 + scol, sAlo + ldsoff);
        async16(Blo + (size_t)r * ldb + k0 + scol, sBlo + ldsoff);
      }
    }
    __syncthreads();

    bf16x8 ah[4], bh[4], al[4], bl[4];
#pragma unroll
    for (int i = 0; i < 4; ++i) {
      const int ra = (wm * 64 + i * 16 + fcol) * 32 + quad * 8;
      const int rb = (wn * 64 + i * 16 + fcol) * 32 + quad * 8;
      ah[i] = *(const bf16x8*)(sAhi + ra);
      bh[i] = *(const bf16x8*)(sBhi + rb);
      if constexpr (SPLIT) {
        al[i] = *(const bf16x8*)(sAlo + ra);
        bl[i] = *(const bf16x8*)(sBlo + rb);
      }
    }
#pragma unroll
    for (int i = 0; i < 4; ++i)
#pragma unroll
      for (int j = 0; j < 4; ++j) {
        acc[i][j] = __builtin_amdgcn_mfma_f32_16x16x32_bf16(ah[i], bh[j], acc[i][j], 0, 0, 0);
        if constexpr (SPLIT) {
          acc[i][j] = __builtin_amdgcn_mfma_f32_16x16x32_bf16(ah[i], bl[j], acc[i][j], 0, 0, 0);
          acc[i][j] = __builtin_amdgcn_mfma_f32_16x16x32_bf16(al[i], bh[j], acc[i][j], 0, 0, 0);
        }
      }
    __syncthreads();
  }
}

#define EPI_SETUP                                                  \
  const int lane = threadIdx.x & 63;                               \
  const int w_   = threadIdx.x >> 6;                               \
  const int wm   = w_ >> 1, wn = w_ & 1;                           \
  const int quad = lane >> 4, fcol = lane & 15;

// --------------------------------------------------------------- split ----
__global__ __launch_bounds__(256) void split_kernel(
    const float* __restrict__ in, unsigned short* __restrict__ hi,
    unsigned short* __restrict__ lo, int n4)
{
  int i = blockIdx.x * 256 + threadIdx.x;
  if (i >= n4) return;
  float4 v = ((const float4*)in)[i];
  ushort4 h, l;
  h.x = f2bf(v.x); l.x = f2bf(v.x - bf2f(h.x));
  h.y = f2bf(v.y); l.y = f2bf(v.y - bf2f(h.y));
  h.z = f2bf(v.z); l.z = f2bf(v.z - bf2f(h.z));
  h.w = f2bf(v.w); l.w = f2bf(v.w - bf2f(h.w));
  ((ushort4*)hi)[i] = h;
  ((ushort4*)lo)[i] = l;
}

// ------------------------------------------------------------- proj QK ----
// O[m][o] = x[m][:] . W[o][:] + bias[o], output re-split to (hi,lo) bf16
__global__ __launch_bounds__(256) void proj_qk_kernel(
    const unsigned short* __restrict__ xhi, const unsigned short* __restrict__ xlo,
    const unsigned short* __restrict__ whi, const unsigned short* __restrict__ wlo,
    const float* __restrict__ bias,
    unsigned short* __restrict__ Ohi, unsigned short* __restrict__ Olo)
{
  __shared__ unsigned short sAhi[128 * 32], sAlo[128 * 32];
  __shared__ unsigned short sBhi[128 * 32], sBlo[128 * 32];
  const int m0 = blockIdx.y * 128, n0 = blockIdx.x * 128;
  f32x4 acc[4][4];
#pragma unroll
  for (int i = 0; i < 4; ++i)
#pragma unroll
    for (int j = 0; j < 4; ++j) acc[i][j] = (f32x4){0.f, 0.f, 0.f, 0.f};

  gemm_mainloop<true>(xhi + (size_t)m0 * DIM, xlo + (size_t)m0 * DIM,
                      whi + (size_t)n0 * DIM, wlo + (size_t)n0 * DIM,
                      DIM, DIM, DIM, sAhi, sAlo, sBhi, sBlo, acc);
  EPI_SETUP
#pragma unroll
  for (int i = 0; i < 4; ++i)
#pragma unroll
    for (int j = 0; j < 4; ++j)
#pragma unroll
      for (int r = 0; r < 4; ++r) {
        const int row = m0 + wm * 64 + i * 16 + quad * 4 + r;
        const int col = n0 + wn * 64 + j * 16 + fcol;
        float v = acc[i][j][r] + bias[col];
        unsigned short h = f2bf(v);
        unsigned short l = f2bf(v - bf2f(h));
        Ohi[(size_t)row * DIM + col] = h;
        Olo[(size_t)row * DIM + col] = l;
      }
}

// -------------------------------------------------------------- proj V ----
// Vt[d][m] = Wv[d][:] . x[m][:] + bv[d]   (A = Wv, B = x; bias per ROW)
__global__ __launch_bounds__(256) void proj_v_kernel(
    const unsigned short* __restrict__ wvhi, const unsigned short* __restrict__ wvlo,
    const unsigned short* __restrict__ xhi, const unsigned short* __restrict__ xlo,
    const float* __restrict__ bias, unsigned short* __restrict__ Vt)
{
  __shared__ unsigned short sAhi[128 * 32], sAlo[128 * 32];
  __shared__ unsigned short sBhi[128 * 32], sBlo[128 * 32];
  const int m0 = blockIdx.y * 128, n0 = blockIdx.x * 128;
  f32x4 acc[4][4];
#pragma unroll
  for (int i = 0; i < 4; ++i)
#pragma unroll
    for (int j = 0; j < 4; ++j) acc[i][j] = (f32x4){0.f, 0.f, 0.f, 0.f};

  gemm_mainloop<true>(wvhi + (size_t)m0 * DIM, wvlo + (size_t)m0 * DIM,
                      xhi + (size_t)n0 * DIM, xlo + (size_t)n0 * DIM,
                      DIM, DIM, DIM, sAhi, sAlo, sBhi, sBlo, acc);
  EPI_SETUP
#pragma unroll
  for (int i = 0; i < 4; ++i)
#pragma unroll
    for (int j = 0; j < 4; ++j)
#pragma unroll
      for (int r = 0; r < 4; ++r) {
        const int row = m0 + wm * 64 + i * 16 + quad * 4 + r;   // d
        const int col = n0 + wn * 64 + j * 16 + fcol;           // seq
        Vt[(size_t)row * MSEQ + col] = f2bf(acc[i][j][r] + bias[row]);
      }
}

// -------------------------------------------------------------- scores ----
// Wbf[b][q][k] = bf16( adj[b][q][k] * exp( Q[b][q][:] . K[b][k][:] ) )
__global__ __launch_bounds__(256) void scores_kernel(
    const unsigned short* __restrict__ Qhi, const unsigned short* __restrict__ Qlo,
    const unsigned short* __restrict__ Khi, const unsigned short* __restrict__ Klo,
    const float* __restrict__ adj, unsigned short* __restrict__ Wbf)
{
  __shared__ unsigned short sAhi[128 * 32], sAlo[128 * 32];
  __shared__ unsigned short sBhi[128 * 32], sBlo[128 * 32];
  const int b  = blockIdx.z;
  const int m0 = blockIdx.y * 128, n0 = blockIdx.x * 128;
  const size_t boff = (size_t)b * SEQ * DIM;
  f32x4 acc[4][4];
#pragma unroll
  for (int i = 0; i < 4; ++i)
#pragma unroll
    for (int j = 0; j < 4; ++j) acc[i][j] = (f32x4){0.f, 0.f, 0.f, 0.f};

  gemm_mainloop<true>(Qhi + boff + (size_t)m0 * DIM, Qlo + boff + (size_t)m0 * DIM,
                      Khi + boff + (size_t)n0 * DIM, Klo + boff + (size_t)n0 * DIM,
                      DIM, DIM, DIM, sAhi, sAlo, sBhi, sBlo, acc);
  EPI_SETUP
#pragma unroll
  for (int i = 0; i < 4; ++i)
#pragma unroll
    for (int j = 0; j < 4; ++j)
#pragma unroll
      for (int r = 0; r < 4; ++r) {
        const int row = m0 + wm * 64 + i * 16 + quad * 4 + r;   // q
        const int col = n0 + wn * 64 + j * 16 + fcol;           // k
        const size_t idx = ((size_t)b * SEQ + row) * SEQ + col;
        float wv = adj[idx] * __expf(acc[i][j][r]);
        Wbf[idx] = f2bf(wv);
      }
}

// ----------------------------------------------------------------- den ----
// den[row] = sum_k bf2f(Wbf[row][k])  — one wave per row, 4 rows per block
__global__ __launch_bounds__(256) void den_kernel(
    const unsigned short* __restrict__ Wbf, float* __restrict__ den)
{
  const int w    = threadIdx.x >> 6;
  const int lane = threadIdx.x & 63;
  const int row  = blockIdx.x * 4 + w;
  const unsigned short* p = Wbf + (size_t)row * SEQ + lane * 8;
  float s = 0.f;
#pragma unroll
  for (int t = 0; t < 4; ++t) {
    uint4 v = *(const uint4*)(p + t * 512);
    s += bf2f((unsigned short)(v.x & 0xffff)) + bf2f((unsigned short)(v.x >> 16));
    s += bf2f((unsigned short)(v.y & 0xffff)) + bf2f((unsigned short)(v.y >> 16));
    s += bf2f((unsigned short)(v.z & 0xffff)) + bf2f((unsigned short)(v.z >> 16));
    s += bf2f((unsigned short)(v.w & 0xffff)) + bf2f((unsigned short)(v.w >> 16));
  }
#pragma unroll
  for (int off = 32; off > 0; off >>= 1) s += __shfl_down(s, off);
  if (lane == 0) den[row] = s;
}

// ----------------------------------------------------------------- agg ----
// out[b][q][d] = ( sum_k Wbf[b][q][k] * Vt[d][b*SEQ+k] ) / den[b*SEQ+q]
__global__ __launch_bounds__(256) void agg_kernel(
    const unsigned short* __restrict__ Wbf, const unsigned short* __restrict__ Vt,
    const float* __restrict__ den, float* __restrict__ out)
{
  __shared__ unsigned short sA[128 * 32], sB[128 * 32];
  const int b  = blockIdx.z;
  const int m0 = blockIdx.y * 128;   // q
  const int n0 = blockIdx.x * 128;   // d
  f32x4 acc[4][4];
#pragma unroll
  for (int i = 0; i < 4; ++i)
#pragma unroll
    for (int j = 0; j < 4; ++j) acc[i][j] = (f32x4){0.f, 0.f, 0.f, 0.f};

  gemm_mainloop<false>(Wbf + ((size_t)b * SEQ + m0) * SEQ, nullptr,
                       Vt + (size_t)n0 * MSEQ + (size_t)b * SEQ, nullptr,
                       SEQ, MSEQ, SEQ, sA, nullptr, sB, nullptr, acc);
  EPI_SETUP
#pragma unroll
  for (int i = 0; i < 4; ++i)
#pragma unroll
    for (int j = 0; j < 4; ++j)
#pragma unroll
      for (int r = 0; r < 4; ++r) {
        const int row = m0 + wm * 64 + i * 16 + quad * 4 + r;   // q
        const int col = n0 + wn * 64 + j * 16 + fcol;           // d
        float dv = den[b * SEQ + row];
        out[((size_t)b * SEQ + row) * DIM + col] = acc[i][j][r] / dv;
      }
}

// -------------------------------------------------------------- launch ----
extern "C" void kernel_launch(void* const* d_in, const int* in_sizes, int n_in,
                              void* d_out, int out_size, void* d_ws, size_t ws_size,
                              hipStream_t stream) {
  const float* x   = (const float*)d_in[0];
  const float* adj = (const float*)d_in[1];
  const float* Wq  = (const float*)d_in[2];
  const float* bq  = (const float*)d_in[3];
  const float* Wk  = (const float*)d_in[4];
  const float* bk  = (const float*)d_in[5];
  const float* Wv  = (const float*)d_in[6];
  const float* bv  = (const float*)d_in[7];
  float* out = (float*)d_out;

  const size_t NX = (size_t)MSEQ * DIM;   // 8,388,608
  const size_t NW = (size_t)DIM * DIM;    // 262,144
  unsigned short* ws = (unsigned short*)d_ws;
  unsigned short* xhi  = ws;              unsigned short* xlo  = xhi + NX;
  unsigned short* wqhi = xlo + NX;        unsigned short* wqlo = wqhi + NW;
  unsigned short* wkhi = wqlo + NW;       unsigned short* wklo = wkhi + NW;
  unsigned short* wvhi = wklo + NW;       unsigned short* wvlo = wvhi + NW;
  unsigned short* Qhi  = wvlo + NW;       unsigned short* Qlo  = Qhi + NX;
  unsigned short* Khi  = Qlo + NX;        unsigned short* Klo  = Khi + NX;
  unsigned short* Vt   = Klo + NX;
  unsigned short* Wbf  = Vt + NX;                       // MSEQ*SEQ
  float* den = (float*)(Wbf + (size_t)MSEQ * SEQ);      // MSEQ floats

  // 1. split fp32 -> bf16 hi/lo
  split_kernel<<<(int)(NX / 4 / 256), 256, 0, stream>>>(x, xhi, xlo, (int)(NX / 4));
  split_kernel<<<(int)(NW / 4 / 256), 256, 0, stream>>>(Wq, wqhi, wqlo, (int)(NW / 4));
  split_kernel<<<(int)(NW / 4 / 256), 256, 0, stream>>>(Wk, wkhi, wklo, (int)(NW / 4));
  split_kernel<<<(int)(NW / 4 / 256), 256, 0, stream>>>(Wv, wvhi, wvlo, (int)(NW / 4));

  // 2. projections
  dim3 pq(DIM / 128, MSEQ / 128);          // (4, 128)
  proj_qk_kernel<<<pq, 256, 0, stream>>>(xhi, xlo, wqhi, wqlo, bq, Qhi, Qlo);
  proj_qk_kernel<<<pq, 256, 0, stream>>>(xhi, xlo, wkhi, wklo, bk, Khi, Klo);
  dim3 pv(MSEQ / 128, DIM / 128);          // (128, 4)
  proj_v_kernel<<<pv, 256, 0, stream>>>(wvhi, wvlo, xhi, xlo, bv, Vt);

  // 3. scores + 4. den + 5. aggregate
  dim3 sg(SEQ / 128, SEQ / 128, BATCH);    // (16, 16, 8)
  scores_kernel<<<sg, 256, 0, stream>>>(Qhi, Qlo, Khi, Klo, adj, Wbf);
  den_kernel<<<MSEQ / 4, 256, 0, stream>>>(Wbf, den);
  dim3 ag(DIM / 128, SEQ / 128, BATCH);    // (4, 16, 8)
  agg_kernel<<<ag, 256, 0, stream>>>(Wbf, Vt, den, out);
}

// Round 3
// 423.472 us; speedup vs baseline: 3.0284x; 1.1931x over previous
//
#include <hip/hip_runtime.h>
#include <hip/hip_bf16.h>

// GraphLayer B=8,N=2048,D=512 — Round 3: fp16 single-MFMA for Q/K path.
//   fp16 (11-bit mantissa) logits: noise sigma ~2e-3 -> exp error <=1.3%,
//   well inside threshold; kills the 3x hi/lo split MFMA + 2x staging.
//   W = adj*exp(logits) MUST stay bf16 (values reach ~1e14 > fp16 max),
//   so agg stays bf16 (W bf16, V bf16) — unchanged from round 2 (passed).
//   den fused into scores epilogue: shuffle-reduce over fcol lanes +
//   atomicAdd, summing the SAME bf16-rounded W values (cancellation).
// All GEMMs: m97 structure — 128x128 tile, BK=32, 256 thr (2x2 waves),
// global_load_lds width=16 staging, 2-barrier K-loop.

#define BATCH 8
#define SEQ   2048
#define DIM   512
#define MSEQ  (BATCH * SEQ)   // 16384

typedef __attribute__((ext_vector_type(8))) short    bf16x8;
typedef __attribute__((ext_vector_type(8))) _Float16 f16x8;
typedef __attribute__((ext_vector_type(4))) _Float16 f16x4;
typedef __attribute__((ext_vector_type(4))) float    f32x4;

__device__ __forceinline__ unsigned short f2bf(float f) {
  __hip_bfloat16 h = __float2bfloat16(f);
  union { __hip_bfloat16 h; unsigned short u; } c; c.h = h; return c.u;
}
__device__ __forceinline__ float bf2f(unsigned short u) {
  union { unsigned int u; float f; } c; c.u = ((unsigned int)u) << 16; return c.f;
}
__device__ __forceinline__ unsigned short f2h(float f) {
  union { _Float16 h; unsigned short u; } c; c.h = (_Float16)f; return c.u;
}

__device__ __forceinline__ void async16(const unsigned short* g, unsigned short* l) {
  __builtin_amdgcn_global_load_lds(
      (const __attribute__((address_space(1))) void*)g,
      (__attribute__((address_space(3))) void*)l, 16, 0, 0);
}

// ---------------------------------------------------------------- core ----
// acc[i][j] += A[m][k] * B[n][k]  (NT). DT=0: bf16 MFMA, DT=1: f16 MFMA.
// A/B pre-offset to the block's first row; elements are 2B (ushort-aliased).
template <int DT>
__device__ __forceinline__ void gemm_mainloop(
    const unsigned short* __restrict__ A, const unsigned short* __restrict__ B,
    int lda, int ldb, int K,
    unsigned short* sA, unsigned short* sB, f32x4 acc[4][4])
{
  const int tid  = threadIdx.x;
  const int lane = tid & 63;
  const int w    = tid >> 6;
  const int wm   = w >> 1, wn = w & 1;
  const int quad = lane >> 4, fcol = lane & 15;
  const int srow = lane >> 2;          // 0..15 within a 16-row chunk
  const int scol = (lane & 3) * 8;     // ushort offset, 16B granules

  for (int k0 = 0; k0 < K; k0 += 32) {
#pragma unroll
    for (int inst = 0; inst < 2; ++inst) {
      const int rbase  = w * 32 + inst * 16;   // wave-uniform
      const int r      = rbase + srow;
      const int ldsoff = rbase * 32;           // row stride 32 ushorts
      async16(A + (size_t)r * lda + k0 + scol, sA + ldsoff);
      async16(B + (size_t)r * ldb + k0 + scol, sB + ldsoff);
    }
    __syncthreads();

#pragma unroll
    for (int i = 0; i < 4; ++i) {
      const int ra = (wm * 64 + i * 16 + fcol) * 32 + quad * 8;
      const int rb = (wn * 64 + i * 16 + fcol) * 32 + quad * 8;
      if constexpr (DT == 0) {
        bf16x8 a = *(const bf16x8*)(sA + ra);
#pragma unroll
        for (int j = 0; j < 4; ++j) {
          const int rbj = (wn * 64 + j * 16 + fcol) * 32 + quad * 8;
          bf16x8 b = *(const bf16x8*)(sB + rbj);
          acc[i][j] = __builtin_amdgcn_mfma_f32_16x16x32_bf16(a, b, acc[i][j], 0, 0, 0);
        }
      } else {
        f16x8 a = *(const f16x8*)(sA + ra);
#pragma unroll
        for (int j = 0; j < 4; ++j) {
          const int rbj = (wn * 64 + j * 16 + fcol) * 32 + quad * 8;
          f16x8 b = *(const f16x8*)(sB + rbj);
          acc[i][j] = __builtin_amdgcn_mfma_f32_16x16x32_f16(a, b, acc[i][j], 0, 0, 0);
        }
      }
      (void)rb;
    }
    __syncthreads();
  }
}

#define EPI_SETUP                                                  \
  const int lane = threadIdx.x & 63;                               \
  const int w_   = threadIdx.x >> 6;                               \
  const int wm   = w_ >> 1, wn = w_ & 1;                           \
  const int quad = lane >> 4, fcol = lane & 15;

// ----------------------------------------------------------------- cvt ----
__global__ __launch_bounds__(256) void cvt_kernel(
    const float* __restrict__ in, unsigned short* __restrict__ out, int n4)
{
  int i = blockIdx.x * 256 + threadIdx.x;
  if (i >= n4) return;
  float4 v = ((const float4*)in)[i];
  ushort4 h;
  h.x = f2h(v.x); h.y = f2h(v.y); h.z = f2h(v.z); h.w = f2h(v.w);
  ((ushort4*)out)[i] = h;
}

// ------------------------------------------------------------- proj QK ----
// O[m][o] = x[m][:] . W[o][:] + bias[o]   (all fp16, fp32 acc)
__global__ __launch_bounds__(256) void proj_qk_kernel(
    const unsigned short* __restrict__ xh, const unsigned short* __restrict__ wh,
    const float* __restrict__ bias, unsigned short* __restrict__ O)
{
  __shared__ unsigned short sA[128 * 32], sB[128 * 32];
  const int m0 = blockIdx.y * 128, n0 = blockIdx.x * 128;
  f32x4 acc[4][4];
#pragma unroll
  for (int i = 0; i < 4; ++i)
#pragma unroll
    for (int j = 0; j < 4; ++j) acc[i][j] = (f32x4){0.f, 0.f, 0.f, 0.f};

  gemm_mainloop<1>(xh + (size_t)m0 * DIM, wh + (size_t)n0 * DIM,
                   DIM, DIM, DIM, sA, sB, acc);
  EPI_SETUP
#pragma unroll
  for (int i = 0; i < 4; ++i)
#pragma unroll
    for (int j = 0; j < 4; ++j)
#pragma unroll
      for (int r = 0; r < 4; ++r) {
        const int row = m0 + wm * 64 + i * 16 + quad * 4 + r;
        const int col = n0 + wn * 64 + j * 16 + fcol;
        O[(size_t)row * DIM + col] = f2h(acc[i][j][r] + bias[col]);
      }
}

// -------------------------------------------------------------- proj V ----
// Vt[d][m] = Wv[d][:] . x[m][:] + bv[d]   (fp16 in, bf16 out, transposed)
__global__ __launch_bounds__(256) void proj_v_kernel(
    const unsigned short* __restrict__ wvh, const unsigned short* __restrict__ xh,
    const float* __restrict__ bias, unsigned short* __restrict__ Vt)
{
  __shared__ unsigned short sA[128 * 32], sB[128 * 32];
  const int m0 = blockIdx.y * 128, n0 = blockIdx.x * 128;
  f32x4 acc[4][4];
#pragma unroll
  for (int i = 0; i < 4; ++i)
#pragma unroll
    for (int j = 0; j < 4; ++j) acc[i][j] = (f32x4){0.f, 0.f, 0.f, 0.f};

  gemm_mainloop<1>(wvh + (size_t)m0 * DIM, xh + (size_t)n0 * DIM,
                   DIM, DIM, DIM, sA, sB, acc);
  EPI_SETUP
#pragma unroll
  for (int i = 0; i < 4; ++i)
#pragma unroll
    for (int j = 0; j < 4; ++j)
#pragma unroll
      for (int r = 0; r < 4; ++r) {
        const int row = m0 + wm * 64 + i * 16 + quad * 4 + r;   // d
        const int col = n0 + wn * 64 + j * 16 + fcol;           // seq
        Vt[(size_t)row * MSEQ + col] = f2bf(acc[i][j][r] + bias[row]);
      }
}

// -------------------------------------------------------------- scores ----
// Wbf[b][q][k] = bf16( adj[b][q][k] * exp( Q[b][q][:] . K[b][k][:] ) )
// den[b*SEQ+q] += rowsum of the SAME bf16-rounded values (atomics).
__global__ __launch_bounds__(256) void scores_kernel(
    const unsigned short* __restrict__ Qh, const unsigned short* __restrict__ Kh,
    const float* __restrict__ adj, unsigned short* __restrict__ Wbf,
    float* __restrict__ den)
{
  __shared__ unsigned short sA[128 * 32], sB[128 * 32];
  const int b  = blockIdx.z;
  const int m0 = blockIdx.y * 128, n0 = blockIdx.x * 128;
  const size_t boff = (size_t)b * SEQ * DIM;
  f32x4 acc[4][4];
#pragma unroll
  for (int i = 0; i < 4; ++i)
#pragma unroll
    for (int j = 0; j < 4; ++j) acc[i][j] = (f32x4){0.f, 0.f, 0.f, 0.f};

  gemm_mainloop<1>(Qh + boff + (size_t)m0 * DIM, Kh + boff + (size_t)n0 * DIM,
                   DIM, DIM, DIM, sA, sB, acc);
  EPI_SETUP
#pragma unroll
  for (int i = 0; i < 4; ++i)
#pragma unroll
    for (int r = 0; r < 4; ++r) {
      const int row = m0 + wm * 64 + i * 16 + quad * 4 + r;     // q
      float s = 0.f;
#pragma unroll
      for (int j = 0; j < 4; ++j) {
        const int col = n0 + wn * 64 + j * 16 + fcol;           // k
        const size_t idx = ((size_t)b * SEQ + row) * SEQ + col;
        unsigned short wu = f2bf(adj[idx] * __expf(acc[i][j][r]));
        Wbf[idx] = wu;
        s += bf2f(wu);
      }
      // reduce over the 16 fcol lanes (bits 0..3 of lane id)
      s += __shfl_xor(s, 1);
      s += __shfl_xor(s, 2);
      s += __shfl_xor(s, 4);
      s += __shfl_xor(s, 8);
      if (fcol == 0) atomicAdd(&den[b * SEQ + row], s);
    }
}

// ----------------------------------------------------------------- agg ----
// out[b][q][d] = ( sum_k Wbf[b][q][k] * Vt[d][b*SEQ+k] ) / den[b*SEQ+q]
__global__ __launch_bounds__(256) void agg_kernel(
    const unsigned short* __restrict__ Wbf, const unsigned short* __restrict__ Vt,
    const float* __restrict__ den, float* __restrict__ out)
{
  __shared__ unsigned short sA[128 * 32], sB[128 * 32];
  const int b  = blockIdx.z;
  const int m0 = blockIdx.y * 128;   // q
  const int n0 = blockIdx.x * 128;   // d
  f32x4 acc[4][4];
#pragma unroll
  for (int i = 0; i < 4; ++i)
#pragma unroll
    for (int j = 0; j < 4; ++j) acc[i][j] = (f32x4){0.f, 0.f, 0.f, 0.f};

  gemm_mainloop<0>(Wbf + ((size_t)b * SEQ + m0) * SEQ,
                   Vt + (size_t)n0 * MSEQ + (size_t)b * SEQ,
                   SEQ, MSEQ, SEQ, sA, sB, acc);
  EPI_SETUP
#pragma unroll
  for (int i = 0; i < 4; ++i)
#pragma unroll
    for (int j = 0; j < 4; ++j)
#pragma unroll
      for (int r = 0; r < 4; ++r) {
        const int row = m0 + wm * 64 + i * 16 + quad * 4 + r;   // q
        const int col = n0 + wn * 64 + j * 16 + fcol;           // d
        float dv = den[b * SEQ + row];
        out[((size_t)b * SEQ + row) * DIM + col] = acc[i][j][r] / dv;
      }
}

// -------------------------------------------------------------- launch ----
extern "C" void kernel_launch(void* const* d_in, const int* in_sizes, int n_in,
                              void* d_out, int out_size, void* d_ws, size_t ws_size,
                              hipStream_t stream) {
  const float* x   = (const float*)d_in[0];
  const float* adj = (const float*)d_in[1];
  const float* Wq  = (const float*)d_in[2];
  const float* bq  = (const float*)d_in[3];
  const float* Wk  = (const float*)d_in[4];
  const float* bk  = (const float*)d_in[5];
  const float* Wv  = (const float*)d_in[6];
  const float* bv  = (const float*)d_in[7];
  float* out = (float*)d_out;

  const size_t NX = (size_t)MSEQ * DIM;   // 8,388,608
  const size_t NW = (size_t)DIM * DIM;    // 262,144
  unsigned short* ws = (unsigned short*)d_ws;
  unsigned short* xh  = ws;               // fp16
  unsigned short* wqh = xh + NX;
  unsigned short* wkh = wqh + NW;
  unsigned short* wvh = wkh + NW;
  unsigned short* Qh  = wvh + NW;         // fp16
  unsigned short* Kh  = Qh + NX;          // fp16
  unsigned short* Vt  = Kh + NX;          // bf16, transposed [DIM][MSEQ]
  unsigned short* Wbf = Vt + NX;          // bf16, MSEQ*SEQ
  float* den = (float*)(Wbf + (size_t)MSEQ * SEQ);   // MSEQ floats

  hipMemsetAsync(den, 0, MSEQ * sizeof(float), stream);

  // 1. fp32 -> fp16 conversions
  cvt_kernel<<<(int)(NX / 4 / 256), 256, 0, stream>>>(x, xh, (int)(NX / 4));
  cvt_kernel<<<(int)(NW / 4 / 256), 256, 0, stream>>>(Wq, wqh, (int)(NW / 4));
  cvt_kernel<<<(int)(NW / 4 / 256), 256, 0, stream>>>(Wk, wkh, (int)(NW / 4));
  cvt_kernel<<<(int)(NW / 4 / 256), 256, 0, stream>>>(Wv, wvh, (int)(NW / 4));

  // 2. projections
  dim3 pq(DIM / 128, MSEQ / 128);          // (4, 128)
  proj_qk_kernel<<<pq, 256, 0, stream>>>(xh, wqh, bq, Qh);
  proj_qk_kernel<<<pq, 256, 0, stream>>>(xh, wkh, bk, Kh);
  dim3 pv(MSEQ / 128, DIM / 128);          // (128, 4)
  proj_v_kernel<<<pv, 256, 0, stream>>>(wvh, xh, bv, Vt);

  // 3. scores (+den) + 4. aggregate
  dim3 sg(SEQ / 128, SEQ / 128, BATCH);    // (16, 16, 8)
  scores_kernel<<<sg, 256, 0, stream>>>(Qh, Kh, adj, Wbf, den);
  dim3 ag(DIM / 128, SEQ / 128, BATCH);    // (4, 16, 8)
  agg_kernel<<<ag, 256, 0, stream>>>(Wbf, Vt, den, out);
}

// Round 4
// 402.721 us; speedup vs baseline: 3.1844x; 1.0515x over previous
//
#include <hip/hip_runtime.h>
#include <hip/hip_bf16.h>

// GraphLayer B=8,N=2048,D=512 — Round 4.
//   r3 post-mortem: scores was latency-bound in its EPILOGUE (64 scalar adj
//   loads/thread; MfmaUtil 12%, HBM 24%, nothing saturated).
//   Changes:
//   1) scores epilogue: per-wave LDS transpose of the C-fragment, then
//      float4 adj loads + vectorized exp + ushort4 W stores (4x fewer,
//      4x wider memory ops).
//   2) den computed inside agg by an extra MFMA vs an all-ones B-fragment:
//      rowsum lands in C-layout exactly where the divide needs it.
//      Deletes den buffer/memset/atomics entirely (same bf16-rounded
//      values -> normalization cancellation preserved).
//   3) Launch fusion: Q+K proj in one kernel (blockIdx.z), 3 W-cvts in one.
// Numerics: fp16 Q/K path (passed r3, absmax 0.0156), W/V bf16 (W reaches
// ~1e14 — must stay bf16), fp32 accum everywhere.

#define BATCH 8
#define SEQ   2048
#define DIM   512
#define MSEQ  (BATCH * SEQ)   // 16384

typedef __attribute__((ext_vector_type(8))) short    bf16x8;
typedef __attribute__((ext_vector_type(8))) _Float16 f16x8;
typedef __attribute__((ext_vector_type(4))) float    f32x4;

__device__ __forceinline__ unsigned short f2bf(float f) {
  __hip_bfloat16 h = __float2bfloat16(f);
  union { __hip_bfloat16 h; unsigned short u; } c; c.h = h; return c.u;
}
__device__ __forceinline__ float bf2f(unsigned short u) {
  union { unsigned int u; float f; } c; c.u = ((unsigned int)u) << 16; return c.f;
}
__device__ __forceinline__ unsigned short f2h(float f) {
  union { _Float16 h; unsigned short u; } c; c.h = (_Float16)f; return c.u;
}

__device__ __forceinline__ void async16(const unsigned short* g, unsigned short* l) {
  __builtin_amdgcn_global_load_lds(
      (const __attribute__((address_space(1))) void*)g,
      (__attribute__((address_space(3))) void*)l, 16, 0, 0);
}

// ---------------------------------------------------------------- core ----
// acc[i][j] += A[m][k] * B[n][k]  (NT). DT=0: bf16 MFMA, DT=1: f16 MFMA.
// DEN=1 (bf16 only): acc_den[i] += MFMA(a_frag, ones) — rowsums in C-layout.
template <int DT, int DEN>
__device__ __forceinline__ void gemm_mainloop(
    const unsigned short* __restrict__ A, const unsigned short* __restrict__ B,
    int lda, int ldb, int K,
    unsigned short* sA, unsigned short* sB,
    f32x4 acc[4][4], f32x4 acc_den[4])
{
  const int tid  = threadIdx.x;
  const int lane = tid & 63;
  const int w    = tid >> 6;
  const int wm   = w >> 1, wn = w & 1;
  const int quad = lane >> 4, fcol = lane & 15;
  const int srow = lane >> 2;          // 0..15 within a 16-row chunk
  const int scol = (lane & 3) * 8;     // ushort offset, 16B granules

  bf16x8 ones;
#pragma unroll
  for (int t = 0; t < 8; ++t) ones[t] = (short)0x3F80;   // bf16 1.0

  for (int k0 = 0; k0 < K; k0 += 32) {
#pragma unroll
    for (int inst = 0; inst < 2; ++inst) {
      const int rbase  = w * 32 + inst * 16;   // wave-uniform
      const int r      = rbase + srow;
      const int ldsoff = rbase * 32;           // row stride 32 ushorts
      async16(A + (size_t)r * lda + k0 + scol, sA + ldsoff);
      async16(B + (size_t)r * ldb + k0 + scol, sB + ldsoff);
    }
    __syncthreads();

#pragma unroll
    for (int i = 0; i < 4; ++i) {
      const int ra = (wm * 64 + i * 16 + fcol) * 32 + quad * 8;
      if constexpr (DT == 0) {
        bf16x8 a = *(const bf16x8*)(sA + ra);
#pragma unroll
        for (int j = 0; j < 4; ++j) {
          const int rbj = (wn * 64 + j * 16 + fcol) * 32 + quad * 8;
          bf16x8 b = *(const bf16x8*)(sB + rbj);
          acc[i][j] = __builtin_amdgcn_mfma_f32_16x16x32_bf16(a, b, acc[i][j], 0, 0, 0);
        }
        if constexpr (DEN)
          acc_den[i] = __builtin_amdgcn_mfma_f32_16x16x32_bf16(a, ones, acc_den[i], 0, 0, 0);
      } else {
        f16x8 a = *(const f16x8*)(sA + ra);
#pragma unroll
        for (int j = 0; j < 4; ++j) {
          const int rbj = (wn * 64 + j * 16 + fcol) * 32 + quad * 8;
          f16x8 b = *(const f16x8*)(sB + rbj);
          acc[i][j] = __builtin_amdgcn_mfma_f32_16x16x32_f16(a, b, acc[i][j], 0, 0, 0);
        }
      }
    }
    __syncthreads();
  }
}

#define EPI_SETUP                                                  \
  const int lane = threadIdx.x & 63;                               \
  const int w_   = threadIdx.x >> 6;                               \
  const int wm   = w_ >> 1, wn = w_ & 1;                           \
  const int quad = lane >> 4, fcol = lane & 15;

// ----------------------------------------------------------------- cvt ----
__global__ __launch_bounds__(256) void cvt_kernel(
    const float* __restrict__ in, unsigned short* __restrict__ out, int n4)
{
  int i = blockIdx.x * 256 + threadIdx.x;
  if (i >= n4) return;
  float4 v = ((const float4*)in)[i];
  ushort4 h;
  h.x = f2h(v.x); h.y = f2h(v.y); h.z = f2h(v.z); h.w = f2h(v.w);
  ((ushort4*)out)[i] = h;
}

// 3 weight matrices in one launch (blockIdx.y selects)
__global__ __launch_bounds__(256) void cvt_w_kernel(
    const float* __restrict__ w0, const float* __restrict__ w1,
    const float* __restrict__ w2, unsigned short* __restrict__ o0,
    unsigned short* __restrict__ o1, unsigned short* __restrict__ o2, int n4)
{
  int i = blockIdx.x * 256 + threadIdx.x;
  if (i >= n4) return;
  const float* in = (blockIdx.y == 0) ? w0 : (blockIdx.y == 1) ? w1 : w2;
  unsigned short* out = (blockIdx.y == 0) ? o0 : (blockIdx.y == 1) ? o1 : o2;
  float4 v = ((const float4*)in)[i];
  ushort4 h;
  h.x = f2h(v.x); h.y = f2h(v.y); h.z = f2h(v.z); h.w = f2h(v.w);
  ((ushort4*)out)[i] = h;
}

// ------------------------------------------------------------- proj QK ----
// z=0: Q = x@Wq^T+bq ; z=1: K = x@Wk^T+bk   (fp16 in/out, fp32 acc)
__global__ __launch_bounds__(256) void proj_qk_kernel(
    const unsigned short* __restrict__ xh,
    const unsigned short* __restrict__ wq, const unsigned short* __restrict__ wk,
    const float* __restrict__ bq, const float* __restrict__ bk,
    unsigned short* __restrict__ Qh, unsigned short* __restrict__ Kh)
{
  __shared__ unsigned short sA[128 * 32], sB[128 * 32];
  const unsigned short* wh = blockIdx.z ? wk : wq;
  const float* bias        = blockIdx.z ? bk : bq;
  unsigned short* O        = blockIdx.z ? Kh : Qh;
  const int m0 = blockIdx.y * 128, n0 = blockIdx.x * 128;
  f32x4 acc[4][4];
#pragma unroll
  for (int i = 0; i < 4; ++i)
#pragma unroll
    for (int j = 0; j < 4; ++j) acc[i][j] = (f32x4){0.f, 0.f, 0.f, 0.f};

  gemm_mainloop<1, 0>(xh + (size_t)m0 * DIM, wh + (size_t)n0 * DIM,
                      DIM, DIM, DIM, sA, sB, acc, nullptr);
  EPI_SETUP
#pragma unroll
  for (int i = 0; i < 4; ++i)
#pragma unroll
    for (int j = 0; j < 4; ++j)
#pragma unroll
      for (int r = 0; r < 4; ++r) {
        const int row = m0 + wm * 64 + i * 16 + quad * 4 + r;
        const int col = n0 + wn * 64 + j * 16 + fcol;
        O[(size_t)row * DIM + col] = f2h(acc[i][j][r] + bias[col]);
      }
}

// -------------------------------------------------------------- proj V ----
// Vt[d][m] = Wv[d][:] . x[m][:] + bv[d]   (fp16 in, bf16 out, transposed)
__global__ __launch_bounds__(256) void proj_v_kernel(
    const unsigned short* __restrict__ wvh, const unsigned short* __restrict__ xh,
    const float* __restrict__ bias, unsigned short* __restrict__ Vt)
{
  __shared__ unsigned short sA[128 * 32], sB[128 * 32];
  const int m0 = blockIdx.y * 128, n0 = blockIdx.x * 128;
  f32x4 acc[4][4];
#pragma unroll
  for (int i = 0; i < 4; ++i)
#pragma unroll
    for (int j = 0; j < 4; ++j) acc[i][j] = (f32x4){0.f, 0.f, 0.f, 0.f};

  gemm_mainloop<1, 0>(wvh + (size_t)m0 * DIM, xh + (size_t)n0 * DIM,
                      DIM, DIM, DIM, sA, sB, acc, nullptr);
  EPI_SETUP
#pragma unroll
  for (int i = 0; i < 4; ++i)
#pragma unroll
    for (int j = 0; j < 4; ++j)
#pragma unroll
      for (int r = 0; r < 4; ++r) {
        const int row = m0 + wm * 64 + i * 16 + quad * 4 + r;   // d
        const int col = n0 + wn * 64 + j * 16 + fcol;           // seq
        Vt[(size_t)row * MSEQ + col] = f2bf(acc[i][j][r] + bias[row]);
      }
}

// -------------------------------------------------------------- scores ----
// Wbf[b][q][k] = bf16( adj[b][q][k] * exp( Q[b][q][:] . K[b][k][:] ) )
// Epilogue: per-wave LDS transpose -> float4 adj loads, ushort4 stores.
#define EPI_STRIDE 68   // floats; 272B rows (16B-aligned), 2-way banks on write
__global__ __launch_bounds__(256) void scores_kernel(
    const unsigned short* __restrict__ Qh, const unsigned short* __restrict__ Kh,
    const float* __restrict__ adj, unsigned short* __restrict__ Wbf)
{
  // arena: K-loop needs 2*8192 B; epilogue needs 4 waves * 16*68*4 B = 17408 B
  __shared__ __align__(16) char smem[4 * 16 * EPI_STRIDE * 4];
  unsigned short* sA = (unsigned short*)smem;
  unsigned short* sB = sA + 128 * 32;
  float* sEpi = (float*)smem;   // safe: K-loop ends with __syncthreads

  const int b  = blockIdx.z;
  const int m0 = blockIdx.y * 128, n0 = blockIdx.x * 128;
  const size_t boff = (size_t)b * SEQ * DIM;
  f32x4 acc[4][4];
#pragma unroll
  for (int i = 0; i < 4; ++i)
#pragma unroll
    for (int j = 0; j < 4; ++j) acc[i][j] = (f32x4){0.f, 0.f, 0.f, 0.f};

  gemm_mainloop<1, 0>(Qh + boff + (size_t)m0 * DIM, Kh + boff + (size_t)n0 * DIM,
                      DIM, DIM, DIM, sA, sB, acc, nullptr);
  EPI_SETUP
  float* myEpi = sEpi + w_ * (16 * EPI_STRIDE);
  const float* adjb = adj + (size_t)b * SEQ * SEQ;
  unsigned short* wb = Wbf + (size_t)b * SEQ * SEQ;
  const int colg = n0 + wn * 64 + fcol * 4;

#pragma unroll
  for (int i = 0; i < 4; ++i) {
    // transpose: C-fragment -> LDS (wave-private region, no block barrier)
#pragma unroll
    for (int j = 0; j < 4; ++j)
#pragma unroll
      for (int r = 0; r < 4; ++r)
        myEpi[(quad * 4 + r) * EPI_STRIDE + fcol + 16 * j] = acc[i][j][r];
    __builtin_amdgcn_s_waitcnt(0);   // lgkmcnt(0): wave-local ds_write->ds_read
    // coalesced passes: 4 rows per pass, lane owns 4 consecutive cols
#pragma unroll
    for (int p = 0; p < 4; ++p) {
      const int rr = p * 4 + quad;
      const int rowg = m0 + wm * 64 + i * 16 + rr;
      float4 s4 = *(const float4*)(myEpi + rr * EPI_STRIDE + fcol * 4);
      float4 a4 = *(const float4*)(adjb + (size_t)rowg * SEQ + colg);
      ushort4 o;
      o.x = f2bf(a4.x * __expf(s4.x));
      o.y = f2bf(a4.y * __expf(s4.y));
      o.z = f2bf(a4.z * __expf(s4.z));
      o.w = f2bf(a4.w * __expf(s4.w));
      *(ushort4*)(wb + (size_t)rowg * SEQ + colg) = o;
    }
  }
}

// ----------------------------------------------------------------- agg ----
// out[b][q][d] = ( sum_k Wbf[b][q][k] * Vt[d][b*SEQ+k] ) / rowsum_k(Wbf)
// den computed by MFMA vs all-ones B-fragment: lands in C-layout directly.
__global__ __launch_bounds__(256) void agg_kernel(
    const unsigned short* __restrict__ Wbf, const unsigned short* __restrict__ Vt,
    float* __restrict__ out)
{
  __shared__ unsigned short sA[128 * 32], sB[128 * 32];
  const int b  = blockIdx.z;
  const int m0 = blockIdx.y * 128;   // q
  const int n0 = blockIdx.x * 128;   // d
  f32x4 acc[4][4];
  f32x4 acc_den[4];
#pragma unroll
  for (int i = 0; i < 4; ++i) {
    acc_den[i] = (f32x4){0.f, 0.f, 0.f, 0.f};
#pragma unroll
    for (int j = 0; j < 4; ++j) acc[i][j] = (f32x4){0.f, 0.f, 0.f, 0.f};
  }

  gemm_mainloop<0, 1>(Wbf + ((size_t)b * SEQ + m0) * SEQ,
                      Vt + (size_t)n0 * MSEQ + (size_t)b * SEQ,
                      SEQ, MSEQ, SEQ, sA, sB, acc, acc_den);
  EPI_SETUP
#pragma unroll
  for (int i = 0; i < 4; ++i)
#pragma unroll
    for (int r = 0; r < 4; ++r) {
      const int row = m0 + wm * 64 + i * 16 + quad * 4 + r;     // q
      const float rd = 1.0f / acc_den[i][r];
#pragma unroll
      for (int j = 0; j < 4; ++j) {
        const int col = n0 + wn * 64 + j * 16 + fcol;           // d
        out[((size_t)b * SEQ + row) * DIM + col] = acc[i][j][r] * rd;
      }
    }
}

// -------------------------------------------------------------- launch ----
extern "C" void kernel_launch(void* const* d_in, const int* in_sizes, int n_in,
                              void* d_out, int out_size, void* d_ws, size_t ws_size,
                              hipStream_t stream) {
  const float* x   = (const float*)d_in[0];
  const float* adj = (const float*)d_in[1];
  const float* Wq  = (const float*)d_in[2];
  const float* bq  = (const float*)d_in[3];
  const float* Wk  = (const float*)d_in[4];
  const float* bk  = (const float*)d_in[5];
  const float* Wv  = (const float*)d_in[6];
  const float* bv  = (const float*)d_in[7];
  float* out = (float*)d_out;

  const size_t NX = (size_t)MSEQ * DIM;   // 8,388,608
  const size_t NW = (size_t)DIM * DIM;    // 262,144
  unsigned short* ws = (unsigned short*)d_ws;
  unsigned short* xh  = ws;               // fp16
  unsigned short* wqh = xh + NX;
  unsigned short* wkh = wqh + NW;
  unsigned short* wvh = wkh + NW;
  unsigned short* Qh  = wvh + NW;         // fp16
  unsigned short* Kh  = Qh + NX;          // fp16
  unsigned short* Vt  = Kh + NX;          // bf16, transposed [DIM][MSEQ]
  unsigned short* Wbf = Vt + NX;          // bf16, MSEQ*SEQ

  // 1. fp32 -> fp16 conversions (2 launches)
  cvt_kernel<<<(int)(NX / 4 / 256), 256, 0, stream>>>(x, xh, (int)(NX / 4));
  dim3 cw((int)(NW / 4 / 256), 3);
  cvt_w_kernel<<<cw, 256, 0, stream>>>(Wq, Wk, Wv, wqh, wkh, wvh, (int)(NW / 4));

  // 2. projections (2 launches)
  dim3 pq(DIM / 128, MSEQ / 128, 2);       // (4, 128, 2) — z: Q or K
  proj_qk_kernel<<<pq, 256, 0, stream>>>(xh, wqh, wkh, bq, bk, Qh, Kh);
  dim3 pv(MSEQ / 128, DIM / 128);          // (128, 4)
  proj_v_kernel<<<pv, 256, 0, stream>>>(wvh, xh, bv, Vt);

  // 3. scores + 4. aggregate
  dim3 sg(SEQ / 128, SEQ / 128, BATCH);    // (16, 16, 8)
  scores_kernel<<<sg, 256, 0, stream>>>(Qh, Kh, adj, Wbf);
  dim3 ag(DIM / 128, SEQ / 128, BATCH);    // (4, 16, 8)
  agg_kernel<<<ag, 256, 0, stream>>>(Wbf, Vt, out);
}